// Round 1
// baseline (306.101 us; speedup 1.0000x reference)
//
#include <hip/hip_runtime.h>
#include <hip/hip_bf16.h>

#define M_DIM 12608   // 64*197
#define K_DIM 768
#define N_DIM 3072
#define M_PAD 12672   // 99*128
#define BM 128
#define BN 128
#define BK 64

typedef __attribute__((ext_vector_type(8))) short bf16x8;
typedef __attribute__((ext_vector_type(4))) float f32x4;

__device__ __forceinline__ void gload_lds16(const void* g, void* l) {
  __builtin_amdgcn_global_load_lds(
      (const __attribute__((address_space(1))) unsigned int*)g,
      (__attribute__((address_space(3))) unsigned int*)l,
      16, 0, 0);
}

// fp32 -> bf16, 8 elements/thread; zero-fill the M_PAD tail so GEMM never reads OOB.
__global__ void cvt_x(const float* __restrict__ x, __hip_bfloat16* __restrict__ xb) {
  size_t i = ((size_t)blockIdx.x * blockDim.x + threadIdx.x) * 8;
  if (i >= (size_t)M_PAD * K_DIM) return;
  union { __hip_bfloat16 h[8]; uint4 u; } o;
  if (i < (size_t)M_DIM * K_DIM) {   // M_DIM*K_DIM divisible by 8, boundary is clean
    float4 a = *(const float4*)(x + i);
    float4 b = *(const float4*)(x + i + 4);
    o.h[0] = __float2bfloat16(a.x); o.h[1] = __float2bfloat16(a.y);
    o.h[2] = __float2bfloat16(a.z); o.h[3] = __float2bfloat16(a.w);
    o.h[4] = __float2bfloat16(b.x); o.h[5] = __float2bfloat16(b.y);
    o.h[6] = __float2bfloat16(b.z); o.h[7] = __float2bfloat16(b.w);
  } else {
    o.u = make_uint4(0, 0, 0, 0);
  }
  *(uint4*)(xb + i) = o.u;
}

// 2:4 mask + fp32 -> bf16. One thread per group of 4 along K.
// Keep the 2 largest |w|; ties: top_k(-|w|) prunes lower index first,
// i.e. keep rank<2 where rank counts (|wj|>|wi|) || (|wj|==|wi| && j>i).
__global__ void cvt_w(const float* __restrict__ w, __hip_bfloat16* __restrict__ wb) {
  size_t g = (size_t)blockIdx.x * blockDim.x + threadIdx.x;
  if (g >= (size_t)N_DIM * (K_DIM / 4)) return;
  float4 v = *(const float4*)(w + g * 4);
  float val[4] = {v.x, v.y, v.z, v.w};
  float a[4] = {fabsf(v.x), fabsf(v.y), fabsf(v.z), fabsf(v.w)};
  union { __hip_bfloat16 h[4]; uint2 u; } o;
#pragma unroll
  for (int i = 0; i < 4; ++i) {
    int rank = 0;
#pragma unroll
    for (int j = 0; j < 4; ++j)
      rank += (a[j] > a[i]) || (a[j] == a[i] && j > i);
    o.h[i] = __float2bfloat16(rank < 2 ? val[i] : 0.0f);
  }
  *(uint2*)(wb + g * 4) = o.u;
}

// m97-style B^T GEMM: C[M][N] = A[M][K] * B[N][K]^T + bias, bf16 in / fp32 out.
// 128x128 tile, BK=64, 4 waves (2x2), each wave 4x4 of 16x16x32 MFMA.
__global__ __launch_bounds__(256) void gemm_bt(
    const __hip_bfloat16* __restrict__ A,   // [M_PAD][K]
    const __hip_bfloat16* __restrict__ B,   // [N][K]
    const float* __restrict__ bias,         // [N]
    float* __restrict__ C)                  // [M][N]
{
  __shared__ __hip_bfloat16 As[BM * BK];
  __shared__ __hip_bfloat16 Bs[BN * BK];

  const int tid  = threadIdx.x;
  const int lane = tid & 63;
  const int wave = tid >> 6;
  const int wm = wave >> 1, wn = wave & 1;

  const int tile_m = blockIdx.y * BM;
  const int tile_n = blockIdx.x * BN;

  // staging geometry: one global_load_lds call = 64 lanes * 16B = 8 rows of 64 bf16
  const int lrow = lane >> 3;        // row within the 8-row segment
  const int lcol = (lane & 7) * 8;   // col element (8 bf16 = 16B)

  // fragment geometry (A-operand layout: A[m=lane&15][k=(lane>>4)*8+j])
  const int frow = lane & 15;
  const int fcol = (lane >> 4) * 8;

  f32x4 acc[4][4] = {};

  for (int k0 = 0; k0 < K_DIM; k0 += BK) {
    __syncthreads();   // previous iteration's LDS reads must complete
#pragma unroll
    for (int i = 0; i < 4; ++i) {
      const int seg = wave * 4 + i;  // wave-uniform
      gload_lds16(A + (size_t)(tile_m + seg * 8 + lrow) * K_DIM + k0 + lcol,
                  &As[seg * 8 * BK]);
    }
#pragma unroll
    for (int i = 0; i < 4; ++i) {
      const int seg = wave * 4 + i;
      gload_lds16(B + (size_t)(tile_n + seg * 8 + lrow) * K_DIM + k0 + lcol,
                  &Bs[seg * 8 * BK]);
    }
    __syncthreads();   // drains vmcnt(0) for the global_load_lds

#pragma unroll
    for (int kk = 0; kk < BK; kk += 32) {
      bf16x8 af[4], bfr[4];
#pragma unroll
      for (int i = 0; i < 4; ++i)
        af[i] = *(const bf16x8*)&As[(wm * 64 + i * 16 + frow) * BK + kk + fcol];
#pragma unroll
      for (int j = 0; j < 4; ++j)
        bfr[j] = *(const bf16x8*)&Bs[(wn * 64 + j * 16 + frow) * BK + kk + fcol];
#pragma unroll
      for (int i = 0; i < 4; ++i)
#pragma unroll
        for (int j = 0; j < 4; ++j)
          acc[i][j] = __builtin_amdgcn_mfma_f32_16x16x32_bf16(af[i], bfr[j], acc[i][j], 0, 0, 0);
    }
  }

  // epilogue: C/D layout col=lane&15, row=(lane>>4)*4+reg
  const int quad = lane >> 4;
  const int ccol = lane & 15;
#pragma unroll
  for (int j = 0; j < 4; ++j) {
    const int gcol = tile_n + wn * 64 + j * 16 + ccol;
    const float bv = bias[gcol];
#pragma unroll
    for (int i = 0; i < 4; ++i) {
      const int rbase = tile_m + wm * 64 + i * 16 + quad * 4;
#pragma unroll
      for (int r = 0; r < 4; ++r) {
        const int grow = rbase + r;
        if (grow < M_DIM)
          C[(size_t)grow * N_DIM + gcol] = acc[i][j][r] + bv;
      }
    }
  }
}

extern "C" void kernel_launch(void* const* d_in, const int* in_sizes, int n_in,
                              void* d_out, int out_size, void* d_ws, size_t ws_size,
                              hipStream_t stream) {
  const float* x    = (const float*)d_in[0];
  const float* w    = (const float*)d_in[1];
  const float* bias = (const float*)d_in[2];
  float* out = (float*)d_out;

  __hip_bfloat16* xb = (__hip_bfloat16*)d_ws;                  // [M_PAD][K]  19.46 MB
  __hip_bfloat16* wb = xb + (size_t)M_PAD * K_DIM;             // [N][K]       4.72 MB

  cvt_x<<<(M_PAD * K_DIM / 8 + 255) / 256, 256, 0, stream>>>(x, xb);
  cvt_w<<<(N_DIM * (K_DIM / 4) + 255) / 256, 256, 0, stream>>>(w, wb);

  dim3 grid(N_DIM / BN, M_PAD / BM);   // 24 x 99 = 2376 blocks
  gemm_bt<<<grid, 256, 0, stream>>>(xb, wb, bias, out);
}

// Round 2
// 278.561 us; speedup vs baseline: 1.0989x; 1.0989x over previous
//
#include <hip/hip_runtime.h>
#include <hip/hip_bf16.h>

#define M_DIM 12608   // 64*197
#define K_DIM 768
#define N_DIM 3072
#define M_PAD 12672   // 99*128
#define BM 128
#define BN 128
#define BK 32

typedef __attribute__((ext_vector_type(8))) short bf16x8;
typedef __attribute__((ext_vector_type(4))) float f32x4;

__device__ __forceinline__ void gload_lds16(const void* g, void* l) {
  __builtin_amdgcn_global_load_lds(
      (const __attribute__((address_space(1))) unsigned int*)g,
      (__attribute__((address_space(3))) unsigned int*)l,
      16, 0, 0);
}

// fp32 -> bf16, 8 elements/thread; zero-fill the M_PAD tail so GEMM never reads OOB.
__global__ void cvt_x(const float* __restrict__ x, __hip_bfloat16* __restrict__ xb) {
  size_t i = ((size_t)blockIdx.x * blockDim.x + threadIdx.x) * 8;
  if (i >= (size_t)M_PAD * K_DIM) return;
  union { __hip_bfloat16 h[8]; uint4 u; } o;
  if (i < (size_t)M_DIM * K_DIM) {
    float4 a = *(const float4*)(x + i);
    float4 b = *(const float4*)(x + i + 4);
    o.h[0] = __float2bfloat16(a.x); o.h[1] = __float2bfloat16(a.y);
    o.h[2] = __float2bfloat16(a.z); o.h[3] = __float2bfloat16(a.w);
    o.h[4] = __float2bfloat16(b.x); o.h[5] = __float2bfloat16(b.y);
    o.h[6] = __float2bfloat16(b.z); o.h[7] = __float2bfloat16(b.w);
  } else {
    o.u = make_uint4(0, 0, 0, 0);
  }
  *(uint4*)(xb + i) = o.u;
}

// 2:4 mask + fp32 -> bf16. One thread per group of 4 along K.
__global__ void cvt_w(const float* __restrict__ w, __hip_bfloat16* __restrict__ wb) {
  size_t g = (size_t)blockIdx.x * blockDim.x + threadIdx.x;
  if (g >= (size_t)N_DIM * (K_DIM / 4)) return;
  float4 v = *(const float4*)(w + g * 4);
  float val[4] = {v.x, v.y, v.z, v.w};
  float a[4] = {fabsf(v.x), fabsf(v.y), fabsf(v.z), fabsf(v.w)};
  union { __hip_bfloat16 h[4]; uint2 u; } o;
#pragma unroll
  for (int i = 0; i < 4; ++i) {
    int rank = 0;
#pragma unroll
    for (int j = 0; j < 4; ++j)
      rank += (a[j] > a[i]) || (a[j] == a[i] && j > i);
    o.h[i] = __float2bfloat16(rank < 2 ? val[i] : 0.0f);
  }
  *(uint2*)(wb + g * 4) = o.u;
}

// B^T GEMM: C[M][N] = A[M][K] * B[N][K]^T + bias, bf16 in / fp32 out.
// 128x128 tile, BK=32, double-buffered LDS (one barrier/iter),
// XOR-swizzled LDS layout for conflict-free ds_read_b128,
// LDS-transpose epilogue with coalesced dwordx4 stores.
//
// LDS map (per 16 KB buffer): A tile @ +0 (8 KB), B tile @ +8192 (8 KB).
// Element (row, cg) of a 128x32 tile (cg = 8-bf16 column group 0..3) lives at
// byte  row*64 + (cg ^ (row&3) ^ ((row>>2)&3)) * 16.
// Staging writes lane i -> base + i*16, so lane i fetches global
// (row = i>>2, cg = (i&3) ^ f(row)) — still 64B-coalesced per 4-lane group.
__global__ __launch_bounds__(256) void gemm_bt(
    const __hip_bfloat16* __restrict__ A,   // [M_PAD][K]
    const __hip_bfloat16* __restrict__ B,   // [N][K]
    const float* __restrict__ bias,         // [N]
    float* __restrict__ C)                  // [M][N]
{
  __shared__ char smem[32768];

  const int tid  = threadIdx.x;
  const int lane = tid & 63;
  const int wave = tid >> 6;
  const int wm = wave >> 1, wn = wave & 1;

  const int tile_m = blockIdx.y * BM;
  const int tile_n = blockIdx.x * BN;

  // ---- staging geometry: wave handles rows [wave*32, wave*32+32) of A and B
  const int ris  = lane >> 2;   // row within 16-row segment
  const int slot = lane & 3;    // 16B slot within the row's 64B
  const int arow0 = wave * 32 + ris;
  const int arow1 = arow0 + 16;
  const int acg0 = slot ^ (arow0 & 3) ^ ((arow0 >> 2) & 3);
  const int acg1 = slot ^ (arow1 & 3) ^ ((arow1 >> 2) & 3);
  const __hip_bfloat16* ag0 = A + (size_t)(tile_m + arow0) * K_DIM + acg0 * 8;
  const __hip_bfloat16* ag1 = A + (size_t)(tile_m + arow1) * K_DIM + acg1 * 8;
  const __hip_bfloat16* bg0 = B + (size_t)(tile_n + arow0) * K_DIM + acg0 * 8;
  const __hip_bfloat16* bg1 = B + (size_t)(tile_n + arow1) * K_DIM + acg1 * 8;

  // ---- fragment geometry (A-operand: lane reads row=lane&15, k=(lane>>4)*8..+8)
  const int frow  = lane & 15;
  const int fslot = (lane >> 4) ^ (lane & 3) ^ ((lane & 15) >> 2);
  const int aoff = (wm * 64 + frow) * 64 + fslot * 16;   // byte offset in A buf
  const int boff = (wn * 64 + frow) * 64 + fslot * 16;   // byte offset in B buf

  f32x4 acc[4][4] = {};

  // prologue: stage k=0 into buffer 0
  {
    char* ba = smem + wave * 2048;
    char* bb = smem + 8192 + wave * 2048;
    gload_lds16(ag0, ba);
    gload_lds16(ag1, ba + 1024);
    gload_lds16(bg0, bb);
    gload_lds16(bg1, bb + 1024);
  }

  const int NITER = K_DIM / BK;   // 24
  for (int k = 0; k < NITER; ++k) {
    const int cur = k & 1;
    __syncthreads();   // drains vmcnt for stage(k); guards buf(cur^1) reuse

    if (k + 1 < NITER) {           // prefetch next tile into the other buffer
      const int off = (k + 1) * BK;
      char* ba = smem + (cur ^ 1) * 16384 + wave * 2048;
      char* bb = smem + (cur ^ 1) * 16384 + 8192 + wave * 2048;
      gload_lds16(ag0 + off, ba);
      gload_lds16(ag1 + off, ba + 1024);
      gload_lds16(bg0 + off, bb);
      gload_lds16(bg1 + off, bb + 1024);
    }

    const char* sa = smem + cur * 16384;
    const char* sb = sa + 8192;
    bf16x8 af[4], bfr[4];
#pragma unroll
    for (int i = 0; i < 4; ++i)
      af[i] = *(const bf16x8*)(sa + aoff + i * 1024);
#pragma unroll
    for (int j = 0; j < 4; ++j)
      bfr[j] = *(const bf16x8*)(sb + boff + j * 1024);
#pragma unroll
    for (int i = 0; i < 4; ++i)
#pragma unroll
      for (int j = 0; j < 4; ++j)
        acc[i][j] = __builtin_amdgcn_mfma_f32_16x16x32_bf16(af[i], bfr[j], acc[i][j], 0, 0, 0);
  }

  // ---- epilogue: per-wave LDS transpose -> coalesced dwordx4 stores
  // C/D layout: col=lane&15, row=(lane>>4)*4+reg
  const int ccol = lane & 15;
  const int quad = lane >> 4;
  float bv[4];
#pragma unroll
  for (int j = 0; j < 4; ++j)
    bv[j] = bias[tile_n + wn * 64 + j * 16 + ccol];

  float* tr = (float*)smem + wave * 1088;   // 16 rows x 68 floats (pad: 2-way banks)
  const int erow = lane >> 2;   // 0..15
  const int eseg = lane & 3;    // 16-float segment within 64 cols

  #pragma unroll
  for (int i = 0; i < 4; ++i) {
    __syncthreads();   // i=0: waves done reading GEMM bufs; others: phase sep
#pragma unroll
    for (int j = 0; j < 4; ++j)
#pragma unroll
      for (int r = 0; r < 4; ++r)
        tr[(quad * 4 + r) * 68 + j * 16 + ccol] = acc[i][j][r] + bv[j];
    __syncthreads();
    const int grow = tile_m + wm * 64 + i * 16 + erow;
    if (grow < M_DIM) {
      float* dst = C + (size_t)grow * N_DIM + tile_n + wn * 64 + eseg * 16;
      const float* src = tr + erow * 68 + eseg * 16;
#pragma unroll
      for (int u = 0; u < 4; ++u)
        *(f32x4*)(dst + u * 4) = *(const f32x4*)(src + u * 4);
    }
  }
}

extern "C" void kernel_launch(void* const* d_in, const int* in_sizes, int n_in,
                              void* d_out, int out_size, void* d_ws, size_t ws_size,
                              hipStream_t stream) {
  const float* x    = (const float*)d_in[0];
  const float* w    = (const float*)d_in[1];
  const float* bias = (const float*)d_in[2];
  float* out = (float*)d_out;

  __hip_bfloat16* xb = (__hip_bfloat16*)d_ws;                  // [M_PAD][K]
  __hip_bfloat16* wb = xb + (size_t)M_PAD * K_DIM;             // [N][K]

  cvt_x<<<(M_PAD * K_DIM / 8 + 255) / 256, 256, 0, stream>>>(x, xb);
  cvt_w<<<(N_DIM * (K_DIM / 4) + 255) / 256, 256, 0, stream>>>(w, wb);

  dim3 grid(N_DIM / BN, M_PAD / BM);   // 24 x 99 = 2376 blocks
  gemm_bt<<<grid, 256, 0, stream>>>(xb, wb, bias, out);
}

// Round 3
// 271.765 us; speedup vs baseline: 1.1263x; 1.0250x over previous
//
#include <hip/hip_runtime.h>
#include <hip/hip_bf16.h>

#define M_DIM 12608   // 64*197
#define K_DIM 768
#define N_DIM 3072
#define M_PAD 12800   // 50*256
#define BM 256
#define BN 128
#define BK 32

typedef __attribute__((ext_vector_type(8))) short bf16x8;
typedef __attribute__((ext_vector_type(4))) float f32x4;

__device__ __forceinline__ void gload_lds16(const void* g, void* l) {
  __builtin_amdgcn_global_load_lds(
      (const __attribute__((address_space(1))) unsigned int*)g,
      (__attribute__((address_space(3))) unsigned int*)l,
      16, 0, 0);
}

// Fused convert: blocks [0, GX) do x fp32->bf16 (+M_PAD zero tail),
// blocks [GX, GX+GW) do 2:4 mask + w fp32->bf16.
#define GX 4800   // M_PAD*K/8/256
#define GW 2304   // N*(K/4)/256
__global__ void cvt_fused(const float* __restrict__ x, const float* __restrict__ w,
                          __hip_bfloat16* __restrict__ xb, __hip_bfloat16* __restrict__ wb) {
  if (blockIdx.x < GX) {
    size_t i = ((size_t)blockIdx.x * 256 + threadIdx.x) * 8;
    union { __hip_bfloat16 h[8]; uint4 u; } o;
    if (i < (size_t)M_DIM * K_DIM) {
      float4 a = *(const float4*)(x + i);
      float4 b = *(const float4*)(x + i + 4);
      o.h[0] = __float2bfloat16(a.x); o.h[1] = __float2bfloat16(a.y);
      o.h[2] = __float2bfloat16(a.z); o.h[3] = __float2bfloat16(a.w);
      o.h[4] = __float2bfloat16(b.x); o.h[5] = __float2bfloat16(b.y);
      o.h[6] = __float2bfloat16(b.z); o.h[7] = __float2bfloat16(b.w);
    } else {
      o.u = make_uint4(0, 0, 0, 0);
    }
    *(uint4*)(xb + i) = o.u;
  } else {
    size_t g = ((size_t)(blockIdx.x - GX) * 256 + threadIdx.x);
    float4 v = *(const float4*)(w + g * 4);
    float val[4] = {v.x, v.y, v.z, v.w};
    float a[4] = {fabsf(v.x), fabsf(v.y), fabsf(v.z), fabsf(v.w)};
    union { __hip_bfloat16 h[4]; uint2 u; } o;
#pragma unroll
    for (int i = 0; i < 4; ++i) {
      int rank = 0;
#pragma unroll
      for (int j = 0; j < 4; ++j)
        rank += (a[j] > a[i]) || (a[j] == a[i] && j > i);
      o.h[i] = __float2bfloat16(rank < 2 ? val[i] : 0.0f);
    }
    *(uint2*)(wb + g * 4) = o.u;
  }
}

// B^T GEMM: C[M][N] = A[M][K]*B[N][K]^T + bias, bf16 in / fp32 out.
// 256x128 block tile, BK=32, 4 waves each computing 64x128 (4x8 MFMA tiles),
// double-buffered LDS with XOR bank swizzle, LDS-transpose epilogue.
//
// LDS per buffer (24 KB): A tile 256x32 @ +0 (16 KB), B tile 128x32 @ +16384 (8 KB).
// Element (row, cg) at byte row*64 + (cg ^ (row&3) ^ ((row>>2)&3))*16.
__global__ __launch_bounds__(256, 2) void gemm_bt(
    const __hip_bfloat16* __restrict__ A,   // [M_PAD][K]
    const __hip_bfloat16* __restrict__ B,   // [N][K]
    const float* __restrict__ bias,         // [N]
    float* __restrict__ C)                  // [M][N]
{
  __shared__ char smem[49152];

  const int tid  = threadIdx.x;
  const int lane = tid & 63;
  const int wave = tid >> 6;

  const int tile_m = blockIdx.y * BM;
  const int tile_n = blockIdx.x * BN;

  // ---- staging geometry (one gload = 16 rows x 64B, lane i -> seg_base + i*16)
  const int ris  = lane >> 2;   // row within 16-row segment
  const int slot = lane & 3;
  const __hip_bfloat16* agp[4];
  const __hip_bfloat16* bgp[2];
#pragma unroll
  for (int i = 0; i < 4; ++i) {
    const int arow = wave * 64 + i * 16 + ris;
    const int acg = slot ^ (arow & 3) ^ ((arow >> 2) & 3);
    agp[i] = A + (size_t)(tile_m + arow) * K_DIM + acg * 8;
  }
#pragma unroll
  for (int i = 0; i < 2; ++i) {
    const int brow = wave * 32 + i * 16 + ris;
    const int bcg = slot ^ (brow & 3) ^ ((brow >> 2) & 3);
    bgp[i] = B + (size_t)(tile_n + brow) * K_DIM + bcg * 8;
  }

  // ---- fragment geometry (A-operand: row=lane&15, k=(lane>>4)*8..+8)
  const int frow  = lane & 15;
  const int fslot = (lane >> 4) ^ (frow & 3) ^ ((frow >> 2) & 3);

  f32x4 acc[4][8] = {};

  // prologue: stage k=0 into buffer 0
#pragma unroll
  for (int i = 0; i < 4; ++i)
    gload_lds16(agp[i], smem + (wave * 4 + i) * 1024);
#pragma unroll
  for (int i = 0; i < 2; ++i)
    gload_lds16(bgp[i], smem + 16384 + (wave * 2 + i) * 1024);

  const int NITER = K_DIM / BK;   // 24
#pragma unroll 2
  for (int k = 0; k < NITER; ++k) {
    const int cur = k & 1;
    __syncthreads();   // drains vmcnt for stage(k); guards buf(cur^1) reuse

    if (k + 1 < NITER) {
      const int off = (k + 1) * BK;
      char* bb = smem + (cur ^ 1) * 24576;
#pragma unroll
      for (int i = 0; i < 4; ++i)
        gload_lds16(agp[i] + off, bb + (wave * 4 + i) * 1024);
#pragma unroll
      for (int i = 0; i < 2; ++i)
        gload_lds16(bgp[i] + off, bb + 16384 + (wave * 2 + i) * 1024);
    }

    const char* sa = smem + cur * 24576;
    bf16x8 af[4], bfr[8];
#pragma unroll
    for (int i = 0; i < 4; ++i)
      af[i] = *(const bf16x8*)(sa + (wave * 64 + i * 16 + frow) * 64 + fslot * 16);
#pragma unroll
    for (int j = 0; j < 8; ++j)
      bfr[j] = *(const bf16x8*)(sa + 16384 + (j * 16 + frow) * 64 + fslot * 16);
#pragma unroll
    for (int i = 0; i < 4; ++i)
#pragma unroll
      for (int j = 0; j < 8; ++j)
        acc[i][j] = __builtin_amdgcn_mfma_f32_16x16x32_bf16(af[i], bfr[j], acc[i][j], 0, 0, 0);
  }

  // ---- epilogue: per-wave LDS transpose -> coalesced dwordx4 stores
  // C/D layout: col=lane&15, row=(lane>>4)*4+reg
  const int ccol = lane & 15;
  const int quad = lane >> 4;
  float bv[8];
#pragma unroll
  for (int j = 0; j < 8; ++j)
    bv[j] = bias[tile_n + j * 16 + ccol];

  float* tr = (float*)smem + wave * 2112;   // 16 rows x 132 floats (pad 4)
  const int erow = lane >> 2;   // 0..15
  const int eseg = lane & 3;    // 32-float segment of the 128-col row

#pragma unroll
  for (int i = 0; i < 4; ++i) {
    __syncthreads();   // i=0: all waves done with GEMM bufs; others: phase sep
#pragma unroll
    for (int j = 0; j < 8; ++j)
#pragma unroll
      for (int r = 0; r < 4; ++r)
        tr[(quad * 4 + r) * 132 + j * 16 + ccol] = acc[i][j][r] + bv[j];
    __syncthreads();
    const int grow = tile_m + wave * 64 + i * 16 + erow;
    if (grow < M_DIM) {
      float* dst = C + (size_t)grow * N_DIM + tile_n + eseg * 32;
      const float* src = tr + erow * 132 + eseg * 32;
#pragma unroll
      for (int u = 0; u < 8; ++u)
        *(f32x4*)(dst + u * 4) = *(const f32x4*)(src + u * 4);
    }
  }
}

extern "C" void kernel_launch(void* const* d_in, const int* in_sizes, int n_in,
                              void* d_out, int out_size, void* d_ws, size_t ws_size,
                              hipStream_t stream) {
  const float* x    = (const float*)d_in[0];
  const float* w    = (const float*)d_in[1];
  const float* bias = (const float*)d_in[2];
  float* out = (float*)d_out;

  __hip_bfloat16* xb = (__hip_bfloat16*)d_ws;                  // [M_PAD][K]
  __hip_bfloat16* wb = xb + (size_t)M_PAD * K_DIM;             // [N][K]

  cvt_fused<<<GX + GW, 256, 0, stream>>>(x, w, xb, wb);

  dim3 grid(N_DIM / BN, M_PAD / BM);   // 24 x 50 = 1200 blocks
  gemm_bt<<<grid, 256, 0, stream>>>(xb, wb, bias, out);
}